// Round 1
// baseline (103.854 us; speedup 1.0000x reference)
//
#include <hip/hip_runtime.h>
#include <hip/hip_bf16.h>
#include <stdint.h>

#define N_NODES 4096
#define N_EDGES 131072
#define C_IN 256
#define C_OUT 256
#define N_HEADS 4
#define C_HEAD 64
#define MAX_DEG 128
#define GEMM_BLOCKS 1024
#define SCAT_BLOCKS 128

typedef __attribute__((ext_vector_type(8))) short short8;
typedef __attribute__((ext_vector_type(4))) short short4v;
typedef __attribute__((ext_vector_type(4))) float floatx4;

union f32u { float f; uint32_t u; };
__device__ __forceinline__ float bf2f(short s) {
    f32u v; v.u = ((uint32_t)(uint16_t)s) << 16; return v.f;
}
__device__ __forceinline__ short f2bf(float f) {
    __hip_bfloat16 h = __float2bfloat16(f);
    return *reinterpret_cast<short*>(&h);
}

// ---- K1: gemm (blocks 0..1023) + scatter (blocks 1024..1151) ----
// gemm: feats = x @ W^T + b (fp32 in, bf16 MFMA fp32-accum, bf16 out)
//       epilogue additionally accumulates the per-node attention scores
//       s_src[n,h] = feats_f32[n]·a[h,:64], s_dst[n,h] = feats_f32[n]·a[h,64:]
//       via 16-lane shfl reduce + atomicAdd (arrays pre-zeroed by memset).
// scatter: capped CSR from edge_index (dedup at aggregation)
__global__ __launch_bounds__(256) void k1_gemm_scatter(
    const float* __restrict__ x, const float* __restrict__ W,
    const float* __restrict__ b, const float* __restrict__ a,
    const int* __restrict__ ei,
    unsigned short* __restrict__ nbr, int* __restrict__ deg,
    __hip_bfloat16* __restrict__ feats,
    float* __restrict__ ssrc_g, float* __restrict__ sdst_g)
{
    int blk = blockIdx.x;
    int tid = threadIdx.x;
    if (blk < GEMM_BLOCKS) {
        int lane = tid & 63;
        int wave = tid >> 6;
        int tile = blk * 4 + wave;                 // 4096 tiles
        int row0 = (tile >> 4) * 16;
        int col0 = (tile & 15) * 16;
        int r    = lane & 15;
        int quad = lane >> 4;

        const floatx4* ax = (const floatx4*)(x + (size_t)(row0 + r) * C_IN);
        const floatx4* bw = (const floatx4*)(W + (size_t)(col0 + r) * C_IN);

        floatx4 acc = {0.f, 0.f, 0.f, 0.f};
        #pragma unroll
        for (int k8 = 0; k8 < 8; ++k8) {           // K=256, steps of 32; frag k = quad*8+j
            floatx4 a0 = ax[k8 * 8 + quad * 2], a1 = ax[k8 * 8 + quad * 2 + 1];
            floatx4 b0 = bw[k8 * 8 + quad * 2], b1 = bw[k8 * 8 + quad * 2 + 1];
            short8 av, bq;
            #pragma unroll
            for (int j = 0; j < 4; ++j) {
                av[j] = f2bf(a0[j]); av[4 + j] = f2bf(a1[j]);
                bq[j] = f2bf(b0[j]); bq[4 + j] = f2bf(b1[j]);
            }
            acc = __builtin_amdgcn_mfma_f32_16x16x32_bf16(av, bq, acc, 0, 0, 0);
        }
        // C/D layout: col = lane&15, row = quad*4 + reg (HW-verified)
        int gn = col0 + r;
        int h  = col0 >> 6;                        // head is uniform per 16-col tile
        float bias = b[gn];
        float avs = a[h * 2 * C_HEAD + (gn & 63)];
        float avd = a[h * 2 * C_HEAD + C_HEAD + (gn & 63)];
        #pragma unroll
        for (int rr = 0; rr < 4; ++rr) {
            int gm = row0 + quad * 4 + rr;
            float v = acc[rr] + bias;              // fp32 feats value (pre-rounding)
            feats[(size_t)gm * C_OUT + gn] = __float2bfloat16(v);
            // per-row partial dots over this tile's 16 cols; reduce across the
            // 16 lanes of this quad (all share gm for fixed rr)
            float s = v * avs;
            float d = v * avd;
            s += __shfl_xor(s, 1, 16); s += __shfl_xor(s, 2, 16);
            s += __shfl_xor(s, 4, 16); s += __shfl_xor(s, 8, 16);
            d += __shfl_xor(d, 1, 16); d += __shfl_xor(d, 2, 16);
            d += __shfl_xor(d, 4, 16); d += __shfl_xor(d, 8, 16);
            if (r == 0) {
                atomicAdd(&ssrc_g[gm * N_HEADS + h], s);
                atomicAdd(&sdst_g[gm * N_HEADS + h], d);
            }
        }
    } else {
        // scatter: 128 blocks x 256 thr x 4 edges
        // int64 edge_index (ref dtype): odd int32 words are all 0 (uniform scalar loads)
        bool is64 = true;
        #pragma unroll
        for (int q = 1; q < 64; q += 2) is64 = is64 && (ei[q] == 0);
        int base = (blk - GEMM_BLOCKS) * 256 + tid;      // 0..32767
        #pragma unroll
        for (int qq = 0; qq < 4; ++qq) {
            int e = base + qq * (SCAT_BLOCKS * 256);
            int row, col;
            if (is64) {
                const long long* e64 = (const long long*)ei;
                row = (int)e64[e];            // edge_index[0, e] -> output row i
                col = (int)e64[N_EDGES + e];  // edge_index[1, e] -> neighbor j
            } else {
                row = ei[e];
                col = ei[N_EDGES + e];
            }
            int pos = atomicAdd(&deg[row], 1);
            if (pos < MAX_DEG) nbr[row * MAX_DEG + pos] = (unsigned short)col;
        }
    }
}

// ---- K2: fused softmax + aggregation (scores precomputed in K1) ----
// Block = 256 thr = 4 waves, one block per node i.
// Phase A: load list, dedup via LDS bitmap, and compute ALL per-edge softmax
//   weights once (thread t handles edge t, all 4 heads) into a 2 KB LDS table.
// Phase B: hot loop per wave = {LDS j, LDS w, 8B global f_j, 4 FMA} — no
//   cross-lane ops, 4 independent iterations in flight.
// Dedup keeps exactly one copy of duplicate (i,j): duplicates carry identical
// weights, so this matches reference boolean-adjacency semantics.
__global__ __launch_bounds__(256) void aggregate(
    const unsigned short* __restrict__ nbr,
    const int* __restrict__ deg,
    const __hip_bfloat16* __restrict__ feats,
    const float* __restrict__ ssrc_g,
    const float* __restrict__ sdst_g,
    float* __restrict__ out)
{
    int i    = blockIdx.x;
    int t    = threadIdx.x;
    int wv   = t >> 6;
    int lane = t & 63;
    int h    = lane >> 4;

    __shared__ unsigned short lst[MAX_DEG];
    __shared__ floatx4        wts4[MAX_DEG];        // per-edge weight, 4 heads
    __shared__ uint32_t       bmap[N_NODES / 32];   // 512 B
    __shared__ floatx4        redv[4][64];
    __shared__ float          redd[4][64];

    int n = deg[i];
    n = (n < MAX_DEG) ? n : MAX_DEG;

    if (t < n) lst[t] = nbr[i * MAX_DEG + t];
    if (t < N_NODES / 32) bmap[t] = 0u;
    __syncthreads();

    // Phase A: dedup + per-edge weights (once per edge, not per lane-iteration)
    if (t < n) {
        int j = lst[t];
        uint32_t bit = 1u << (j & 31);
        uint32_t old = atomicOr(&bmap[j >> 5], bit);
        bool keep = !(old & bit);
        floatx4 ss = *(const floatx4*)(ssrc_g + i * N_HEADS);   // broadcast
        floatx4 sd = *(const floatx4*)(sdst_g + (size_t)j * N_HEADS);
        floatx4 w;
        #pragma unroll
        for (int hh = 0; hh < N_HEADS; ++hh) {
            float l = ss[hh] + sd[hh];
            l = (l > 0.f) ? l : 0.2f * l;           // leaky_relu, ALPHA = 0.2
            w[hh] = keep ? __expf(fminf(l, 60.f)) : 0.f;
        }
        wts4[t] = w;
    }
    __syncthreads();

    const float* wts = (const float*)wts4;
    floatx4 acc = {0.f, 0.f, 0.f, 0.f};
    float   den = 0.f;

    if (n > 0) {
        #pragma unroll 4
        for (int k = wv; k < n; k += 4) {
            int j = lst[k];
            float w = wts[k * 4 + h];               // broadcast within 16-lane group
            short4v fv = *(const short4v*)(feats + (size_t)j * C_OUT + lane * 4);
            den += w;
            acc[0] += w * bf2f(fv[0]); acc[1] += w * bf2f(fv[1]);
            acc[2] += w * bf2f(fv[2]); acc[3] += w * bf2f(fv[3]);
        }
    } else {
        // ref: all-NEG_FILL row -> uniform softmax over every node
        for (int j = wv; j < N_NODES; j += 4) {
            short4v fv = *(const short4v*)(feats + (size_t)j * C_OUT + lane * 4);
            acc[0] += bf2f(fv[0]); acc[1] += bf2f(fv[1]);
            acc[2] += bf2f(fv[2]); acc[3] += bf2f(fv[3]);
            den += 1.0f;
        }
    }
    redv[wv][lane] = acc;
    redd[wv][lane] = den;
    __syncthreads();

    if (wv == 0) {
        floatx4 r0 = redv[0][lane], r1 = redv[1][lane], r2 = redv[2][lane], r3 = redv[3][lane];
        float d = redd[0][lane] + redd[1][lane] + redd[2][lane] + redd[3][lane];
        if (d <= 0.f) d = 1.f;                  // unreachable guard
        float inv = 1.0f / d;
        floatx4 o;
        o[0] = (r0[0] + r1[0] + r2[0] + r3[0]) * inv;
        o[1] = (r0[1] + r1[1] + r2[1] + r3[1]) * inv;
        o[2] = (r0[2] + r1[2] + r2[2] + r3[2]) * inv;
        o[3] = (r0[3] + r1[3] + r2[3] + r3[3]) * inv;
        *(floatx4*)(out + (size_t)i * C_OUT + lane * 4) = o;
    }
}

extern "C" void kernel_launch(void* const* d_in, const int* in_sizes, int n_in,
                              void* d_out, int out_size, void* d_ws, size_t ws_size,
                              hipStream_t stream) {
    const float* x  = (const float*)d_in[0];
    const int*   ei = (const int*)d_in[1];
    const float* W  = (const float*)d_in[2];
    const float* b  = (const float*)d_in[3];
    const float* a  = (const float*)d_in[4];
    float* out = (float*)d_out;

    // Workspace layout (ws_size is 256 MB; we use ~3.2 MB):
    //   feats @ 0            : 2 MB  (bf16 4096x256)
    //   nbr   @ 2 MB         : 1 MB  (u16 4096x128)
    //   deg   @ 3 MB         : 16 KB
    //   ssrc  @ 3 MB + 16 KB : 64 KB (f32 4096x4)
    //   sdst  @ 3 MB + 80 KB : 64 KB (f32 4096x4)
    uint8_t* ws = (uint8_t*)d_ws;
    __hip_bfloat16* feats = (__hip_bfloat16*)ws;
    unsigned short* nbr   = (unsigned short*)(ws + (2u << 20));
    int*            deg   = (int*)(ws + (3u << 20));
    float*          ssrc  = (float*)(ws + (3u << 20) + (16u << 10));
    float*          sdst  = (float*)(ws + (3u << 20) + (80u << 10));

    // zero deg + ssrc + sdst in one contiguous memset (16 KB + 64 KB + 64 KB)
    hipMemsetAsync(deg, 0, (144u << 10), stream);
    k1_gemm_scatter<<<GEMM_BLOCKS + SCAT_BLOCKS, 256, 0, stream>>>(
        x, W, b, a, ei, nbr, deg, feats, ssrc, sdst);
    aggregate<<<N_NODES, 256, 0, stream>>>(nbr, deg, feats, ssrc, sdst, out);
}